// Round 1
// baseline (4617.896 us; speedup 1.0000x reference)
//
#include <hip/hip_runtime.h>
#include <math.h>

#define NB 8
#define NT 1500
#define ND 1536
#define NP 1024
#define NE 192
#define NITER 6
#define NEGINF -1e30f

// ---------------- helpers ----------------
__device__ __forceinline__ float block_reduce_sum(float v, float* red) {
    int tid = threadIdx.x;
    red[tid] = v; __syncthreads();
    for (int s = blockDim.x >> 1; s > 0; s >>= 1) {
        if (tid < s) red[tid] += red[tid + s];
        __syncthreads();
    }
    float r = red[0]; __syncthreads();
    return r;
}

// ---------------- pre-pass kernels ----------------
// grid (ND/256, NB, 12), block 256 : raw column sums of h and h^2
__global__ void k_colstats(const float* __restrict__ h, float* __restrict__ sum1,
                           float* __restrict__ sum2) {
    int d = blockIdx.x * 256 + threadIdx.x;
    int b = blockIdx.y;
    int t0 = blockIdx.z * 125, t1 = t0 + 125; // 12*125 = 1500
    const float* hp = h + (size_t)b * NT * ND + d;
    float s = 0.f, s2 = 0.f;
    for (int t = t0; t < t1; ++t) { float v = hp[(size_t)t * ND]; s += v; s2 += v * v; }
    atomicAdd(&sum1[b * ND + d], s);
    atomicAdd(&sum2[b * ND + d], s2);
}

// grid 48, block 256: finalize mu0/sigma0 in place
__global__ void k_stats_fin(float* __restrict__ mu0, float* __restrict__ sig0) {
    int i = blockIdx.x * 256 + threadIdx.x;
    float mu = mu0[i] * (1.f / NT);
    float sec = sig0[i] * (1.f / NT);
    mu0[i] = mu;
    sig0[i] = sqrtf(fmaxf(sec - mu * mu, 1e-8f));
}

// grid (NT, NB), block 256: energy mask flag (1.0 keep, 0.0 mask)
__global__ void k_energy(const float* __restrict__ h, float* __restrict__ emask) {
    __shared__ float red[256];
    int t = blockIdx.x, b = blockIdx.y;
    const float* hp = h + ((size_t)b * NT + t) * ND;
    float s = 0.f;
    for (int d = threadIdx.x; d < ND; d += 256) { float v = hp[d]; s += v * v; }
    s = block_reduce_sum(s, red);
    if (threadIdx.x == 0) emask[b * NT + t] = (s * (1.f / ND) > 1e-4f) ? 1.f : 0.f;
}

// grid NP+1, block 256: w2r[p] = mean_d W2[p,d]; block NP computes mean(b2)
__global__ void k_w2r(const float* __restrict__ W2, const float* __restrict__ b2,
                      float* __restrict__ w2r, float* __restrict__ b2m) {
    __shared__ float red[256];
    int p = blockIdx.x;
    float s = 0.f;
    if (p < NP) {
        const float* row = W2 + (size_t)p * ND;
        for (int d = threadIdx.x; d < ND; d += 256) s += row[d];
        s = block_reduce_sum(s, red);
        if (threadIdx.x == 0) w2r[p] = s * (1.f / ND);
    } else {
        for (int d = threadIdx.x; d < ND; d += 256) s += b2[d];
        s = block_reduce_sum(s, red);
        if (threadIdx.x == 0) b2m[0] = s * (1.f / ND);
    }
}

// grid (NP/256, 8), block 256: biasb[b,p] += sum_{d in seg} mu0*W1[D+d,p] + sig0*W1[2D+d,p]
__global__ void k_biasb(const float* __restrict__ W1, const float* __restrict__ mu0,
                        const float* __restrict__ sig0, float* __restrict__ biasb) {
    int p = blockIdx.x * 256 + threadIdx.x;
    int d0 = blockIdx.y * 192, d1 = d0 + 192; // 8*192 = 1536
    float acc[NB];
#pragma unroll
    for (int b = 0; b < NB; ++b) acc[b] = 0.f;
    for (int d = d0; d < d1; ++d) {
        float wa = W1[(size_t)(ND + d) * NP + p];
        float wb = W1[(size_t)(2 * ND + d) * NP + p];
#pragma unroll
        for (int b = 0; b < NB; ++b)
            acc[b] += mu0[b * ND + d] * wa + sig0[b * ND + d] * wb;
    }
#pragma unroll
    for (int b = 0; b < NB; ++b) atomicAdd(&biasb[b * NP + p], acc[b]);
}

// grid (6, NB), block 256: C init, stop init
__global__ void k_init(float* __restrict__ C, const float* __restrict__ C0,
                       float* __restrict__ stopf) {
    int d = blockIdx.x * 256 + threadIdx.x;
    int b = blockIdx.y;
    C[b * ND + d] = C0[d];
    if (blockIdx.x == 0 && threadIdx.x == 0) stopf[b] = 0.f;
}

// ---------------- tiled f32 GEMM ----------------
// Out[b*orpb + r, n] = sum_k f(A[b*NT + t0 + r, k]) * Bm[k, n] + bias[b*bstride + n]
// f = identity, or relu(x + cvec[b,k]) when RELU
template <bool RELU>
__global__ __launch_bounds__(256) void k_gemm(
    const float* __restrict__ Aall, int lda, const float* __restrict__ Bm, int N, int K,
    const float* __restrict__ bias, int bstride, const float* __restrict__ cvec,
    float* __restrict__ Out, int orpb, int t0, int Mrows) {
    int b = blockIdx.z;
    int row0 = blockIdx.x * 128;
    int col0 = blockIdx.y * 128;
    int tid = threadIdx.x;
    int tx = tid & 15, ty = tid >> 4;
    __shared__ float As[16][128];
    __shared__ float Bs[16][128];
    float acc[8][8];
#pragma unroll
    for (int i = 0; i < 8; ++i)
#pragma unroll
        for (int j = 0; j < 8; ++j) acc[i][j] = 0.f;

    const float* Ab = Aall + ((size_t)b * NT + t0) * lda;
    const float* cv = RELU ? (cvec + (size_t)b * K) : (const float*)nullptr;

    int arow = tid >> 2;        // 0..63
    int acol = (tid & 3) * 4;   // 0,4,8,12
    int brow = tid >> 4;        // 0..15
    int bcol = (tid & 15) * 8;  // 0..120

    for (int k0 = 0; k0 < K; k0 += 16) {
#pragma unroll
        for (int half = 0; half < 2; ++half) {
            int r = arow + half * 64;
            int gr = row0 + r;
            float4 v = make_float4(0.f, 0.f, 0.f, 0.f);
            if (gr < Mrows) {
                v = *(const float4*)(Ab + (size_t)gr * lda + k0 + acol);
                if (RELU) {
                    v.x = fmaxf(v.x + cv[k0 + acol + 0], 0.f);
                    v.y = fmaxf(v.y + cv[k0 + acol + 1], 0.f);
                    v.z = fmaxf(v.z + cv[k0 + acol + 2], 0.f);
                    v.w = fmaxf(v.w + cv[k0 + acol + 3], 0.f);
                }
            }
            As[acol + 0][r] = v.x; As[acol + 1][r] = v.y;
            As[acol + 2][r] = v.z; As[acol + 3][r] = v.w;
        }
        {
            const float* bp = Bm + (size_t)(k0 + brow) * N + col0 + bcol;
            float4 u0 = *(const float4*)(bp);
            float4 u1 = *(const float4*)(bp + 4);
            *(float4*)&Bs[brow][bcol] = u0;
            *(float4*)&Bs[brow][bcol + 4] = u1;
        }
        __syncthreads();
#pragma unroll
        for (int k = 0; k < 16; ++k) {
            float a[8], bb[8];
            *(float4*)&a[0] = *(const float4*)&As[k][ty * 8];
            *(float4*)&a[4] = *(const float4*)&As[k][ty * 8 + 4];
            *(float4*)&bb[0] = *(const float4*)&Bs[k][tx * 8];
            *(float4*)&bb[4] = *(const float4*)&Bs[k][tx * 8 + 4];
#pragma unroll
            for (int i = 0; i < 8; ++i)
#pragma unroll
                for (int j = 0; j < 8; ++j) acc[i][j] = fmaf(a[i], bb[j], acc[i][j]);
        }
        __syncthreads();
    }
    const float* bi = bias + (size_t)b * bstride + col0;
#pragma unroll
    for (int i = 0; i < 8; ++i) {
        int r = row0 + ty * 8 + i;
        if (r < Mrows) {
            float* orow = Out + ((size_t)b * orpb + r) * N + col0;
#pragma unroll
            for (int j = 0; j < 8; ++j) orow[tx * 8 + j] = acc[i][j] + bi[tx * 8 + j];
        }
    }
}

// ---------------- per-iteration kernels ----------------
// grid (NP/256, 8), block 256: cvec[b,p] += sum_{d in seg} C[b,d]*Wc[d,p]
__global__ void k_cvec(const float* __restrict__ C, const float* __restrict__ Wc,
                       float* __restrict__ cvec) {
    int p = blockIdx.x * 256 + threadIdx.x;
    int d0 = blockIdx.y * 192, d1 = d0 + 192;
    float acc[NB];
#pragma unroll
    for (int b = 0; b < NB; ++b) acc[b] = 0.f;
    for (int d = d0; d < d1; ++d) {
        float wc = Wc[(size_t)d * NP + p];
#pragma unroll
        for (int b = 0; b < NB; ++b) acc[b] += C[b * ND + d] * wc;
    }
#pragma unroll
    for (int b = 0; b < NB; ++b) atomicAdd(&cvec[b * NP + p], acc[b]);
}

// grid (NT, NB), block 256: att_raw[b,t] = sum_p relu(base+cvec)*w2r + b2mean (masked)
__global__ void k_att(const float* __restrict__ base, const float* __restrict__ cvec,
                      const float* __restrict__ w2r, const float* __restrict__ b2m,
                      const float* __restrict__ emask, float* __restrict__ att) {
    __shared__ float red[256];
    int t = blockIdx.x, b = blockIdx.y;
    const float* br = base + ((size_t)b * NT + t) * NP;
    const float* cv = cvec + (size_t)b * NP;
    float s = 0.f;
    for (int p = threadIdx.x; p < NP; p += 256)
        s += fmaxf(br[p] + cv[p], 0.f) * w2r[p];
    s = block_reduce_sum(s, red);
    if (threadIdx.x == 0) {
        float a = s + b2m[0];
        att[b * NT + t] = (emask[b * NT + t] > 0.5f) ? a : NEGINF;
    }
}

// grid NB, block 256: softmax over T with the reference's renormalization
__global__ void k_softmax(const float* __restrict__ att, float* __restrict__ A) {
    __shared__ float red[256];
    int b = blockIdx.x, tid = threadIdx.x;
    const float* x = att + (size_t)b * NT;
    float* a = A + (size_t)b * NT;
    float mx = -3.4e38f;
    for (int t = tid; t < NT; t += 256) mx = fmaxf(mx, x[t]);
    red[tid] = mx; __syncthreads();
    for (int s = 128; s > 0; s >>= 1) {
        if (tid < s) red[tid] = fmaxf(red[tid], red[tid + s]);
        __syncthreads();
    }
    mx = red[0]; __syncthreads();
    float sm = 0.f;
    for (int t = tid; t < NT; t += 256) { float e = expf(x[t] - mx); a[t] = e; sm += e; }
    float s1 = block_reduce_sum(sm, red);
    float inv1 = 1.f / s1;
    float sm2 = 0.f;
    for (int t = tid; t < NT; t += 256) { float v = a[t] * inv1; a[t] = v; sm2 += v; }
    float s2 = block_reduce_sum(sm2, red);
    float inv2 = 1.f / (s2 + 1e-8f);
    for (int t = tid; t < NT; t += 256) a[t] *= inv2;
}

// grid (ND/256, NB, 12), block 256: accumulate mu_p, second, Ah, zA over chunk rows
__global__ void k_reduce(const float* __restrict__ out2c, const float* __restrict__ h,
                         const float* __restrict__ A, int t0, int Mc, int Tc,
                         float* __restrict__ mup, float* __restrict__ s2p,
                         float* __restrict__ Ah, float* __restrict__ zA) {
    int d = blockIdx.x * 256 + threadIdx.x;
    int b = blockIdx.y;
    int rp = (Mc + 11) / 12;
    int r0 = blockIdx.z * rp, r1 = min(r0 + rp, Mc);
    if (r0 >= r1) return;
    float mu = 0.f, s2 = 0.f, ah = 0.f, za = 0.f;
    for (int r = r0; r < r1; ++r) {
        int t = t0 + r;
        float o = out2c[((size_t)b * Tc + r) * ND + d];
        float hv = h[((size_t)b * NT + t) * ND + d];
        float av = A[b * NT + t];
        mu += o * hv;
        s2 += o * hv * hv;
        ah += av * hv;
        za += av * o;
    }
    atomicAdd(&mup[b * ND + d], mu);
    atomicAdd(&s2p[b * ND + d], s2);
    atomicAdd(&Ah[b * ND + d], ah);
    atomicAdd(&zA[b * ND + d], za);
}

// grid 48, block 256: sigma_p
__global__ void k_sigma(const float* __restrict__ mup, const float* __restrict__ s2p,
                        float* __restrict__ sigp) {
    int i = blockIdx.x * 256 + threadIdx.x;
    float mu = mup[i];
    sigp[i] = sqrtf(fmaxf(s2p[i] - mu * mu, 1e-8f));
}

// grid 16, block 192: embt[b,e] += sum_{d in seg} mu_p*w0[d,e] + sigma_p*w0[D+d,e]
__global__ void k_embacc(const float* __restrict__ mup, const float* __restrict__ sigp,
                         const float* __restrict__ w0, float* __restrict__ embt) {
    int e = threadIdx.x;
    int d0 = blockIdx.x * 96, d1 = d0 + 96; // 16*96 = 1536
    float acc[NB];
#pragma unroll
    for (int b = 0; b < NB; ++b) acc[b] = 0.f;
    for (int d = d0; d < d1; ++d) {
        float wa = w0[(size_t)d * NE + e];
        float wb = w0[(size_t)(ND + d) * NE + e];
#pragma unroll
        for (int b = 0; b < NB; ++b)
            acc[b] += mup[b * ND + d] * wa + sigp[b * ND + d] * wb;
    }
#pragma unroll
    for (int b = 0; b < NB; ++b) atomicAdd(&embt[b * NE + e], acc[b]);
}

// grid NB, block 256: normalize, write E row for iter i
__global__ void k_embnorm(const float* __restrict__ embt, const float* __restrict__ b0,
                          float* __restrict__ Eout, int iter) {
    __shared__ float red[256];
    int b = blockIdx.x, e = threadIdx.x;
    float v = (e < NE) ? (embt[b * NE + e] + b0[e]) : 0.f;
    float s = block_reduce_sum(v * v, red);
    float sc = 1.f / fmaxf(sqrtf(s), 1e-12f);
    if (e < NE) Eout[((size_t)b * NITER + iter) * NE + e] = v * sc;
}

// grid NB, block 256: C update, stop logit, p, stop flag
__global__ void k_stop(const float* __restrict__ zA, const float* __restrict__ Ah,
                       float* __restrict__ C, float* __restrict__ stopf,
                       const float* __restrict__ Wstop, const float* __restrict__ bstop,
                       const float* __restrict__ thr, float* __restrict__ Pout, int iter) {
    __shared__ float red[256];
    int b = blockIdx.x, tid = threadIdx.x;
    float active = (stopf[b] > 0.5f) ? 0.f : 1.f;
    float dsum = 0.f;
    for (int d = tid; d < ND; d += 256) {
        float Cn = C[b * ND + d] + active * (Ah[b * ND + d] * (1.f / NT));
        C[b * ND + d] = Cn;
        dsum += zA[b * ND + d] * Wstop[d] + Cn * Wstop[ND + d];
    }
    float s = block_reduce_sum(dsum, red);
    if (tid == 0) {
        float logit = s + bstop[0];
        float p = 1.f / (1.f + expf(-logit));
        Pout[b * NITER + iter] = p;
        if (p < thr[0]) stopf[b] = 1.f;
    }
}

// grid NB, block 192: apply cumulative stop mask to E
__global__ void k_mask(float* __restrict__ Eout, const float* __restrict__ Pout,
                       const float* __restrict__ thr) {
    __shared__ float run;
    int b = blockIdx.x, tid = threadIdx.x;
    if (tid == 0) run = 1.f;
    __syncthreads();
    for (int j = 0; j < NITER; ++j) {
        if (tid == 0) { if (Pout[b * NITER + j] < thr[0]) run = 0.f; }
        __syncthreads();
        Eout[((size_t)b * NITER + j) * NE + tid] *= run;
        __syncthreads();
    }
}

// ---------------- launch ----------------
extern "C" void kernel_launch(void* const* d_in, const int* in_sizes, int n_in,
                              void* d_out, int out_size, void* d_ws, size_t ws_size,
                              hipStream_t stream) {
    const float* h = (const float*)d_in[0];
    const float* W1 = (const float*)d_in[1];
    const float* Wc = (const float*)d_in[2];
    const float* W2 = (const float*)d_in[3];
    const float* b2 = (const float*)d_in[4];
    const float* w0 = (const float*)d_in[5];
    const float* b0 = (const float*)d_in[6];
    const float* Wstop = (const float*)d_in[7];
    const float* bstop = (const float*)d_in[8];
    const float* thr = (const float*)d_in[9];
    const float* C0 = (const float*)d_in[10];

    float* Eout = (float*)d_out;
    float* Pout = Eout + (size_t)NB * NITER * NE;

    float* ws = (float*)d_ws;
    size_t off = 0;
    auto alloc = [&](size_t n) { float* p = ws + off; off += (n + 3) & ~(size_t)3; return p; };

    float* base = alloc((size_t)NB * NT * NP);
    float* mu0 = alloc(NB * ND);
    float* sig0 = alloc(NB * ND);
    float* emask = alloc(NB * NT);
    float* biasb = alloc(NB * NP);
    float* w2r = alloc(NP);
    float* b2m = alloc(4);
    float* cvec = alloc(NB * NP);
    float* att = alloc(NB * NT);
    float* Abuf = alloc(NB * NT);
    float* mup = alloc(NB * ND);
    float* s2p = alloc(NB * ND);
    float* sigp = alloc(NB * ND);
    float* Ahb = alloc(NB * ND);
    float* zAb = alloc(NB * ND);
    float* Cb = alloc(NB * ND);
    float* stopf = alloc(8);
    float* embt = alloc(NB * NE);
    size_t fixed = off;

    size_t availf = (ws_size / 4 > fixed) ? (ws_size / 4 - fixed) : 0;
    int Tc = (int)(availf / ((size_t)NB * ND));
    if (Tc > NT) Tc = NT;
    if (Tc < 1) Tc = 1;
    int nchunk = (NT + Tc - 1) / Tc;
    float* out2c = ws + off;

    // ---- pre-pass ----
    hipMemsetAsync(mu0, 0, (size_t)NB * ND * 4, stream);
    hipMemsetAsync(sig0, 0, (size_t)NB * ND * 4, stream);
    hipMemsetAsync(biasb, 0, (size_t)NB * NP * 4, stream);
    k_colstats<<<dim3(ND / 256, NB, 12), 256, 0, stream>>>(h, mu0, sig0);
    k_stats_fin<<<dim3(NB * ND / 256), 256, 0, stream>>>(mu0, sig0);
    k_energy<<<dim3(NT, NB), 256, 0, stream>>>(h, emask);
    k_w2r<<<dim3(NP + 1), 256, 0, stream>>>(W2, b2, w2r, b2m);
    k_biasb<<<dim3(NP / 256, 8), 256, 0, stream>>>(W1, mu0, sig0, biasb);
    k_gemm<false><<<dim3((NT + 127) / 128, NP / 128, NB), 256, 0, stream>>>(
        h, ND, W1, NP, ND, biasb, NP, nullptr, base, NT, 0, NT);
    k_init<<<dim3(ND / 256, NB), 256, 0, stream>>>(Cb, C0, stopf);

    // ---- iterations ----
    for (int i = 0; i < NITER; ++i) {
        hipMemsetAsync(cvec, 0, (size_t)NB * NP * 4, stream);
        k_cvec<<<dim3(NP / 256, 8), 256, 0, stream>>>(Cb, Wc, cvec);
        k_att<<<dim3(NT, NB), 256, 0, stream>>>(base, cvec, w2r, b2m, emask, att);
        k_softmax<<<dim3(NB), 256, 0, stream>>>(att, Abuf);
        // zero mup, s2p, sigp, Ahb, zAb (contiguous)
        hipMemsetAsync(mup, 0, (size_t)5 * NB * ND * 4, stream);
        for (int c = 0; c < nchunk; ++c) {
            int t0 = c * Tc;
            int Mc = NT - t0; if (Mc > Tc) Mc = Tc;
            k_gemm<true><<<dim3((Mc + 127) / 128, ND / 128, NB), 256, 0, stream>>>(
                base, NP, W2, ND, NP, b2, 0, cvec, out2c, Tc, t0, Mc);
            k_reduce<<<dim3(ND / 256, NB, 12), 256, 0, stream>>>(
                out2c, h, Abuf, t0, Mc, Tc, mup, s2p, Ahb, zAb);
        }
        k_sigma<<<dim3(NB * ND / 256), 256, 0, stream>>>(mup, s2p, sigp);
        hipMemsetAsync(embt, 0, (size_t)NB * NE * 4, stream);
        k_embacc<<<dim3(16), 192, 0, stream>>>(mup, sigp, w0, embt);
        k_embnorm<<<dim3(NB), 256, 0, stream>>>(embt, b0, Eout, i);
        k_stop<<<dim3(NB), 256, 0, stream>>>(zAb, Ahb, Cb, stopf, Wstop, bstop, thr, Pout, i);
    }
    k_mask<<<dim3(NB), 192, 0, stream>>>(Eout, Pout, thr);
}

// Round 2
// 2169.911 us; speedup vs baseline: 2.1282x; 2.1282x over previous
//
#include <hip/hip_runtime.h>
#include <math.h>

#define NB 8
#define NT 1500
#define ND 1536
#define NP 1024
#define NE 192
#define NITER 6
#define NEGINF -1e30f

typedef __attribute__((ext_vector_type(8))) short bf16x8;
typedef __attribute__((ext_vector_type(4))) float f32x4;
typedef __attribute__((ext_vector_type(8))) unsigned short us16x8;

__device__ __forceinline__ unsigned short bf_rne(float x) {
    unsigned u = __float_as_uint(x);
    return (unsigned short)((u + 0x7FFFu + ((u >> 16) & 1u)) >> 16);
}
__device__ __forceinline__ float bf_f(unsigned short u) {
    return __uint_as_float(((unsigned)u) << 16);
}

// ---------------- helpers ----------------
__device__ __forceinline__ float block_reduce_sum(float v, float* red) {
    int tid = threadIdx.x;
    red[tid] = v; __syncthreads();
    for (int s = blockDim.x >> 1; s > 0; s >>= 1) {
        if (tid < s) red[tid] += red[tid + s];
        __syncthreads();
    }
    float r = red[0]; __syncthreads();
    return r;
}

// ---------------- pre-pass kernels ----------------
__global__ void k_colstats(const float* __restrict__ h, float* __restrict__ sum1,
                           float* __restrict__ sum2) {
    int d = blockIdx.x * 256 + threadIdx.x;
    int b = blockIdx.y;
    int t0 = blockIdx.z * 125, t1 = t0 + 125;
    const float* hp = h + (size_t)b * NT * ND + d;
    float s = 0.f, s2 = 0.f;
    for (int t = t0; t < t1; ++t) { float v = hp[(size_t)t * ND]; s += v; s2 += v * v; }
    atomicAdd(&sum1[b * ND + d], s);
    atomicAdd(&sum2[b * ND + d], s2);
}

__global__ void k_stats_fin(float* __restrict__ mu0, float* __restrict__ sig0) {
    int i = blockIdx.x * 256 + threadIdx.x;
    float mu = mu0[i] * (1.f / NT);
    float sec = sig0[i] * (1.f / NT);
    mu0[i] = mu;
    sig0[i] = sqrtf(fmaxf(sec - mu * mu, 1e-8f));
}

__global__ void k_energy(const float* __restrict__ h, float* __restrict__ emask) {
    __shared__ float red[256];
    int t = blockIdx.x, b = blockIdx.y;
    const float* hp = h + ((size_t)b * NT + t) * ND;
    float s = 0.f;
    for (int d = threadIdx.x; d < ND; d += 256) { float v = hp[d]; s += v * v; }
    s = block_reduce_sum(s, red);
    if (threadIdx.x == 0) emask[b * NT + t] = (s * (1.f / ND) > 1e-4f) ? 1.f : 0.f;
}

__global__ void k_w2r(const float* __restrict__ W2, const float* __restrict__ b2,
                      float* __restrict__ w2r, float* __restrict__ b2m) {
    __shared__ float red[256];
    int p = blockIdx.x;
    float s = 0.f;
    if (p < NP) {
        const float* row = W2 + (size_t)p * ND;
        for (int d = threadIdx.x; d < ND; d += 256) s += row[d];
        s = block_reduce_sum(s, red);
        if (threadIdx.x == 0) w2r[p] = s * (1.f / ND);
    } else {
        for (int d = threadIdx.x; d < ND; d += 256) s += b2[d];
        s = block_reduce_sum(s, red);
        if (threadIdx.x == 0) b2m[0] = s * (1.f / ND);
    }
}

__global__ void k_biasb(const float* __restrict__ W1, const float* __restrict__ mu0,
                        const float* __restrict__ sig0, float* __restrict__ biasb) {
    int p = blockIdx.x * 256 + threadIdx.x;
    int d0 = blockIdx.y * 192, d1 = d0 + 192;
    float acc[NB];
#pragma unroll
    for (int b = 0; b < NB; ++b) acc[b] = 0.f;
    for (int d = d0; d < d1; ++d) {
        float wa = W1[(size_t)(ND + d) * NP + p];
        float wb = W1[(size_t)(2 * ND + d) * NP + p];
#pragma unroll
        for (int b = 0; b < NB; ++b)
            acc[b] += mu0[b * ND + d] * wa + sig0[b * ND + d] * wb;
    }
#pragma unroll
    for (int b = 0; b < NB; ++b) atomicAdd(&biasb[b * NP + p], acc[b]);
}

__global__ void k_init(float* __restrict__ C, const float* __restrict__ C0,
                       float* __restrict__ stopf) {
    int d = blockIdx.x * 256 + threadIdx.x;
    int b = blockIdx.y;
    C[b * ND + d] = C0[d];
    if (blockIdx.x == 0 && threadIdx.x == 0) stopf[b] = 0.f;
}

// ---------------- weight split (once): W [K][N] f32 -> tiled swizzled bf16 hi/lo ----------------
// tile layout: [ntile][kc][128 cols][32 k] with slot swizzle s_store = s ^ ((r>>1)&3)
__global__ void k_split_w(const float* __restrict__ W, int ldw, int kcnt,
                          unsigned short* __restrict__ th, unsigned short* __restrict__ tl) {
    __shared__ float t[128][33];
    int nt = blockIdx.x, kc = blockIdx.y, tid = threadIdx.x;
    int col = tid & 127, kh = tid >> 7;
    const float* wp = W + (size_t)(kc * 32 + kh) * ldw + nt * 128 + col;
#pragma unroll
    for (int i = 0; i < 16; ++i)
        t[col][kh + 2 * i] = wp[(size_t)(2 * i) * ldw];
    __syncthreads();
    int r = tid >> 1;
    int swz = (r >> 1) & 3;
    size_t tb = ((size_t)nt * kcnt + kc) * 4096;
#pragma unroll
    for (int j = 0; j < 2; ++j) {
        int so = (tid & 1) * 2 + j;
        int s = so ^ swz;
        us16x8 hv, lv;
#pragma unroll
        for (int q = 0; q < 8; ++q) {
            float x = t[r][s * 8 + q];
            unsigned short hh = bf_rne(x);
            hv[q] = hh;
            lv[q] = bf_rne(x - bf_f(hh));
        }
        *(us16x8*)&th[tb + r * 32 + so * 8] = hv;
        *(us16x8*)&tl[tb + r * 32 + so * 8] = lv;
    }
}

// ---------------- per-iter: relu(base+cvec) -> tiled swizzled bf16 hi/lo ----------------
// grid (12, 32, NB), block 256
__global__ void k_split_relu(const float* __restrict__ base, const float* __restrict__ cvec,
                             unsigned short* __restrict__ th, unsigned short* __restrict__ tl) {
    int tr = blockIdx.x, kc = blockIdx.y, b = blockIdx.z;
    int tid = threadIdx.x;
    int r = tid >> 1, quad = tid & 1;
    int row = tr * 128 + r;
    bool ok = row < NT;
    size_t tb = ((size_t)(b * 12 + tr) * 32 + kc) * 4096;
    const float* bp = base + ((size_t)b * NT + row) * NP + kc * 32 + quad * 16;
    const float* cv = cvec + b * NP + kc * 32 + quad * 16;
    int swz = (r >> 1) & 3;
#pragma unroll
    for (int i = 0; i < 4; ++i) {
        int kk = quad * 16 + i * 4;
        float x0 = 0.f, x1 = 0.f, x2 = 0.f, x3 = 0.f;
        if (ok) {
            float4 v = *(const float4*)(bp + i * 4);
            float4 c4 = *(const float4*)(cv + i * 4);
            x0 = fmaxf(v.x + c4.x, 0.f); x1 = fmaxf(v.y + c4.y, 0.f);
            x2 = fmaxf(v.z + c4.z, 0.f); x3 = fmaxf(v.w + c4.w, 0.f);
        }
        unsigned short h0 = bf_rne(x0), h1 = bf_rne(x1), h2 = bf_rne(x2), h3 = bf_rne(x3);
        int off = r * 32 + (((kk >> 3) ^ swz) << 3) + (kk & 7);
        *(ushort4*)&th[tb + off] = make_ushort4(h0, h1, h2, h3);
        *(ushort4*)&tl[tb + off] = make_ushort4(bf_rne(x0 - bf_f(h0)), bf_rne(x1 - bf_f(h1)),
                                                bf_rne(x2 - bf_f(h2)), bf_rne(x3 - bf_f(h3)));
    }
}

// ---------------- MFMA GEMM, 3-term bf16 split, fused reduction epilogue ----------------
// RELU=true : A = pre-split relu tiles, K=1024, N=1536; epilogue accumulates mu_p/s2p/zA/Ah
// RELU=false: A = h (f32, on-the-fly split), K=1536, N=1024; epilogue writes base(+biasb)
template <bool RELU>
__global__ __launch_bounds__(256) void k_gemm_mfma(
    const float* __restrict__ hsrc, const unsigned short* __restrict__ at_h,
    const unsigned short* __restrict__ at_l, const unsigned short* __restrict__ bt_h,
    const unsigned short* __restrict__ bt_l, const float* __restrict__ biasv,
    float* __restrict__ Out, const float* __restrict__ Aw,
    float* __restrict__ mup, float* __restrict__ s2p,
    float* __restrict__ zab, float* __restrict__ ahb) {
    constexpr int K = RELU ? NP : ND;
    constexpr int KC = K / 32;
    __shared__ unsigned short As_h[4096], As_l[4096], Bs_h[4096], Bs_l[4096];
    int b = blockIdx.z, tr = blockIdx.x, nt = blockIdx.y;
    int tid = threadIdx.x;
    int lane = tid & 63, w = tid >> 6;
    int wr = w >> 1, wc = w & 1;
    int l15 = lane & 15, kg = lane >> 4;
    int sw = (l15 >> 1) & 3;
    f32x4 acc[4][4];
#pragma unroll
    for (int m = 0; m < 4; ++m)
#pragma unroll
        for (int n = 0; n < 4; ++n) acc[m][n] = (f32x4){0.f, 0.f, 0.f, 0.f};
    int aoff[4], boff[4];
#pragma unroll
    for (int m = 0; m < 4; ++m) aoff[m] = (wr * 64 + m * 16 + l15) * 32 + ((kg ^ sw) << 3);
#pragma unroll
    for (int n = 0; n < 4; ++n) boff[n] = (wc * 64 + n * 16 + l15) * 32 + ((kg ^ sw) << 3);

    const unsigned short* gb_h = bt_h + ((size_t)nt * KC) * 4096 + lane * 8;
    const unsigned short* gb_l = bt_l + ((size_t)nt * KC) * 4096 + lane * 8;
    const unsigned short* ga_h = nullptr;
    const unsigned short* ga_l = nullptr;
    if (RELU) {
        ga_h = at_h + ((size_t)(b * 12 + tr) * KC) * 4096 + lane * 8;
        ga_l = at_l + ((size_t)(b * 12 + tr) * KC) * 4096 + lane * 8;
    }
    // on-the-fly A (base path)
    int r2 = tid >> 1, quad = tid & 1;
    int arow = tr * 128 + r2;
    bool aok = arow < NT;
    int aswz = (r2 >> 1) & 3;
    const float* hp = hsrc + ((size_t)b * NT + arow) * ND + quad * 16;

    for (int kc = 0; kc < KC; ++kc) {
        if (RELU) {
            const unsigned short* gsrc = (w == 0) ? ga_h : (w == 1) ? ga_l : (w == 2) ? gb_h : gb_l;
            unsigned short* ldst = (w == 0) ? As_h : (w == 1) ? As_l : (w == 2) ? Bs_h : Bs_l;
            const unsigned short* src = gsrc + (size_t)kc * 4096;
#pragma unroll
            for (int c = 0; c < 8; ++c)
                __builtin_amdgcn_global_load_lds(src + c * 512, ldst + c * 512, 16, 0, 0);
        } else {
            const unsigned short* gsrc = (w < 2) ? gb_h : gb_l;
            unsigned short* ldst = (w < 2) ? Bs_h : Bs_l;
            const unsigned short* src = gsrc + (size_t)kc * 4096 + (w & 1) * 2048;
#pragma unroll
            for (int c = 0; c < 4; ++c)
                __builtin_amdgcn_global_load_lds(src + c * 512, ldst + (w & 1) * 2048 + c * 512, 16, 0, 0);
#pragma unroll
            for (int i = 0; i < 4; ++i) {
                int kk = quad * 16 + i * 4;
                float x0 = 0.f, x1 = 0.f, x2 = 0.f, x3 = 0.f;
                if (aok) {
                    float4 v = *(const float4*)(hp + kc * 32 + i * 4);
                    x0 = v.x; x1 = v.y; x2 = v.z; x3 = v.w;
                }
                unsigned short h0 = bf_rne(x0), h1 = bf_rne(x1), h2 = bf_rne(x2), h3 = bf_rne(x3);
                int off = r2 * 32 + (((kk >> 3) ^ aswz) << 3) + (kk & 7);
                *(ushort4*)&As_h[off] = make_ushort4(h0, h1, h2, h3);
                *(ushort4*)&As_l[off] = make_ushort4(bf_rne(x0 - bf_f(h0)), bf_rne(x1 - bf_f(h1)),
                                                     bf_rne(x2 - bf_f(h2)), bf_rne(x3 - bf_f(h3)));
            }
        }
        __syncthreads();
        bf16x8 ah[4], al[4];
#pragma unroll
        for (int m = 0; m < 4; ++m) {
            ah[m] = *(const bf16x8*)&As_h[aoff[m]];
            al[m] = *(const bf16x8*)&As_l[aoff[m]];
        }
#pragma unroll
        for (int n = 0; n < 4; ++n) {
            bf16x8 bh = *(const bf16x8*)&Bs_h[boff[n]];
            bf16x8 bl = *(const bf16x8*)&Bs_l[boff[n]];
#pragma unroll
            for (int m = 0; m < 4; ++m) {
                acc[m][n] = __builtin_amdgcn_mfma_f32_16x16x32_bf16(ah[m], bh, acc[m][n], 0, 0, 0);
                acc[m][n] = __builtin_amdgcn_mfma_f32_16x16x32_bf16(ah[m], bl, acc[m][n], 0, 0, 0);
                acc[m][n] = __builtin_amdgcn_mfma_f32_16x16x32_bf16(al[m], bh, acc[m][n], 0, 0, 0);
            }
        }
        __syncthreads();
    }

    int rowb = tr * 128 + wr * 64 + (kg << 2);
    int colb = nt * 128 + wc * 64 + l15;
    if (RELU) {
        float b2c[4];
#pragma unroll
        for (int n = 0; n < 4; ++n) b2c[n] = biasv[colb + n * 16];
        float pm[4] = {0, 0, 0, 0}, ps2[4] = {0, 0, 0, 0}, pza[4] = {0, 0, 0, 0}, pah[4] = {0, 0, 0, 0};
#pragma unroll
        for (int m = 0; m < 4; ++m) {
#pragma unroll
            for (int q = 0; q < 4; ++q) {
                int row = rowb + m * 16 + q;
                bool ok = row < NT;
                int rowc = ok ? row : (NT - 1);
                float okf = ok ? 1.f : 0.f;
                float a = Aw[b * NT + rowc] * okf;
                const float* hrow = hsrc + ((size_t)b * NT + rowc) * ND;
#pragma unroll
                for (int n = 0; n < 4; ++n) {
                    float hv = hrow[colb + n * 16] * okf;
                    float o2 = acc[m][n][q] + b2c[n];
                    pm[n] = fmaf(o2, hv, pm[n]);
                    ps2[n] = fmaf(o2 * hv, hv, ps2[n]);
                    pza[n] = fmaf(a, o2, pza[n]);
                    pah[n] = fmaf(a, hv, pah[n]);
                }
            }
        }
#pragma unroll
        for (int n = 0; n < 4; ++n) {
            pm[n] += __shfl_xor(pm[n], 16); pm[n] += __shfl_xor(pm[n], 32);
            ps2[n] += __shfl_xor(ps2[n], 16); ps2[n] += __shfl_xor(ps2[n], 32);
            pza[n] += __shfl_xor(pza[n], 16); pza[n] += __shfl_xor(pza[n], 32);
            pah[n] += __shfl_xor(pah[n], 16); pah[n] += __shfl_xor(pah[n], 32);
            if (kg == 0) {
                int col = colb + n * 16;
                atomicAdd(&mup[b * ND + col], pm[n]);
                atomicAdd(&s2p[b * ND + col], ps2[n]);
                atomicAdd(&zab[b * ND + col], pza[n]);
                atomicAdd(&ahb[b * ND + col], pah[n]);
            }
        }
    } else {
#pragma unroll
        for (int m = 0; m < 4; ++m)
#pragma unroll
            for (int q = 0; q < 4; ++q) {
                int row = rowb + m * 16 + q;
                if (row < NT) {
                    float* orow = Out + ((size_t)b * NT + row) * NP;
#pragma unroll
                    for (int n = 0; n < 4; ++n)
                        orow[colb + n * 16] = acc[m][n][q] + biasv[b * NP + colb + n * 16];
                }
            }
    }
}

// ---------------- per-iteration small kernels ----------------
__global__ void k_cvec(const float* __restrict__ C, const float* __restrict__ Wc,
                       float* __restrict__ cvec) {
    int p = blockIdx.x * 256 + threadIdx.x;
    int d0 = blockIdx.y * 192, d1 = d0 + 192;
    float acc[NB];
#pragma unroll
    for (int b = 0; b < NB; ++b) acc[b] = 0.f;
    for (int d = d0; d < d1; ++d) {
        float wc = Wc[(size_t)d * NP + p];
#pragma unroll
        for (int b = 0; b < NB; ++b) acc[b] += C[b * ND + d] * wc;
    }
#pragma unroll
    for (int b = 0; b < NB; ++b) atomicAdd(&cvec[b * NP + p], acc[b]);
}

__global__ void k_att(const float* __restrict__ base, const float* __restrict__ cvec,
                      const float* __restrict__ w2r, const float* __restrict__ b2m,
                      const float* __restrict__ emask, float* __restrict__ att) {
    __shared__ float red[256];
    int t = blockIdx.x, b = blockIdx.y;
    const float* br = base + ((size_t)b * NT + t) * NP;
    const float* cv = cvec + (size_t)b * NP;
    float s = 0.f;
    for (int p = threadIdx.x; p < NP; p += 256)
        s += fmaxf(br[p] + cv[p], 0.f) * w2r[p];
    s = block_reduce_sum(s, red);
    if (threadIdx.x == 0) {
        float a = s + b2m[0];
        att[b * NT + t] = (emask[b * NT + t] > 0.5f) ? a : NEGINF;
    }
}

__global__ void k_softmax(const float* __restrict__ att, float* __restrict__ A) {
    __shared__ float red[256];
    int b = blockIdx.x, tid = threadIdx.x;
    const float* x = att + (size_t)b * NT;
    float* a = A + (size_t)b * NT;
    float mx = -3.4e38f;
    for (int t = tid; t < NT; t += 256) mx = fmaxf(mx, x[t]);
    red[tid] = mx; __syncthreads();
    for (int s = 128; s > 0; s >>= 1) {
        if (tid < s) red[tid] = fmaxf(red[tid], red[tid + s]);
        __syncthreads();
    }
    mx = red[0]; __syncthreads();
    float sm = 0.f;
    for (int t = tid; t < NT; t += 256) { float e = expf(x[t] - mx); a[t] = e; sm += e; }
    float s1 = block_reduce_sum(sm, red);
    float inv1 = 1.f / s1;
    float sm2 = 0.f;
    for (int t = tid; t < NT; t += 256) { float v = a[t] * inv1; a[t] = v; sm2 += v; }
    float s2 = block_reduce_sum(sm2, red);
    float inv2 = 1.f / (s2 + 1e-8f);
    for (int t = tid; t < NT; t += 256) a[t] *= inv2;
}

__global__ void k_sigma(const float* __restrict__ mup, const float* __restrict__ s2p,
                        float* __restrict__ sigp) {
    int i = blockIdx.x * 256 + threadIdx.x;
    float mu = mup[i];
    sigp[i] = sqrtf(fmaxf(s2p[i] - mu * mu, 1e-8f));
}

__global__ void k_embacc(const float* __restrict__ mup, const float* __restrict__ sigp,
                         const float* __restrict__ w0, float* __restrict__ embt) {
    int e = threadIdx.x;
    int d0 = blockIdx.x * 96, d1 = d0 + 96;
    float acc[NB];
#pragma unroll
    for (int b = 0; b < NB; ++b) acc[b] = 0.f;
    for (int d = d0; d < d1; ++d) {
        float wa = w0[(size_t)d * NE + e];
        float wb = w0[(size_t)(ND + d) * NE + e];
#pragma unroll
        for (int b = 0; b < NB; ++b)
            acc[b] += mup[b * ND + d] * wa + sigp[b * ND + d] * wb;
    }
#pragma unroll
    for (int b = 0; b < NB; ++b) atomicAdd(&embt[b * NE + e], acc[b]);
}

__global__ void k_embnorm(const float* __restrict__ embt, const float* __restrict__ b0,
                          float* __restrict__ Eout, int iter) {
    __shared__ float red[256];
    int b = blockIdx.x, e = threadIdx.x;
    float v = (e < NE) ? (embt[b * NE + e] + b0[e]) : 0.f;
    float s = block_reduce_sum(v * v, red);
    float sc = 1.f / fmaxf(sqrtf(s), 1e-12f);
    if (e < NE) Eout[((size_t)b * NITER + iter) * NE + e] = v * sc;
}

__global__ void k_stop(const float* __restrict__ zA, const float* __restrict__ Ah,
                       float* __restrict__ C, float* __restrict__ stopf,
                       const float* __restrict__ Wstop, const float* __restrict__ bstop,
                       const float* __restrict__ thr, float* __restrict__ Pout, int iter) {
    __shared__ float red[256];
    int b = blockIdx.x, tid = threadIdx.x;
    float active = (stopf[b] > 0.5f) ? 0.f : 1.f;
    float dsum = 0.f;
    for (int d = tid; d < ND; d += 256) {
        float Cn = C[b * ND + d] + active * (Ah[b * ND + d] * (1.f / NT));
        C[b * ND + d] = Cn;
        dsum += zA[b * ND + d] * Wstop[d] + Cn * Wstop[ND + d];
    }
    float s = block_reduce_sum(dsum, red);
    if (tid == 0) {
        float logit = s + bstop[0];
        float p = 1.f / (1.f + expf(-logit));
        Pout[b * NITER + iter] = p;
        if (p < thr[0]) stopf[b] = 1.f;
    }
}

__global__ void k_mask(float* __restrict__ Eout, const float* __restrict__ Pout,
                       const float* __restrict__ thr) {
    __shared__ float run;
    int b = blockIdx.x, tid = threadIdx.x;
    if (tid == 0) run = 1.f;
    __syncthreads();
    for (int j = 0; j < NITER; ++j) {
        if (tid == 0) { if (Pout[b * NITER + j] < thr[0]) run = 0.f; }
        __syncthreads();
        Eout[((size_t)b * NITER + j) * NE + tid] *= run;
        __syncthreads();
    }
}

// ---------------- launch ----------------
extern "C" void kernel_launch(void* const* d_in, const int* in_sizes, int n_in,
                              void* d_out, int out_size, void* d_ws, size_t ws_size,
                              hipStream_t stream) {
    const float* h = (const float*)d_in[0];
    const float* W1 = (const float*)d_in[1];
    const float* Wc = (const float*)d_in[2];
    const float* W2 = (const float*)d_in[3];
    const float* b2 = (const float*)d_in[4];
    const float* w0 = (const float*)d_in[5];
    const float* b0 = (const float*)d_in[6];
    const float* Wstop = (const float*)d_in[7];
    const float* bstop = (const float*)d_in[8];
    const float* thr = (const float*)d_in[9];
    const float* C0 = (const float*)d_in[10];

    float* Eout = (float*)d_out;
    float* Pout = Eout + (size_t)NB * NITER * NE;

    char* wsb = (char*)d_ws;
    size_t off = 0;
    auto alloc = [&](size_t bytes) -> void* {
        void* p = wsb + off; off += (bytes + 15) & ~(size_t)15; return p;
    };

    float* base = (float*)alloc((size_t)NB * NT * NP * 4);
    unsigned short* rel_h = (unsigned short*)alloc((size_t)NB * 12 * 32 * 4096 * 2);
    unsigned short* rel_l = (unsigned short*)alloc((size_t)NB * 12 * 32 * 4096 * 2);
    unsigned short* w1t_h = (unsigned short*)alloc((size_t)8 * 48 * 4096 * 2);
    unsigned short* w1t_l = (unsigned short*)alloc((size_t)8 * 48 * 4096 * 2);
    unsigned short* w2t_h = (unsigned short*)alloc((size_t)12 * 32 * 4096 * 2);
    unsigned short* w2t_l = (unsigned short*)alloc((size_t)12 * 32 * 4096 * 2);
    float* mu0 = (float*)alloc(NB * ND * 4);
    float* sig0 = (float*)alloc(NB * ND * 4);
    float* emask = (float*)alloc(NB * NT * 4);
    float* biasb = (float*)alloc(NB * NP * 4);
    float* w2r = (float*)alloc(NP * 4);
    float* b2m = (float*)alloc(16);
    float* cvec = (float*)alloc(NB * NP * 4);
    float* att = (float*)alloc(NB * NT * 4);
    float* Abuf = (float*)alloc(NB * NT * 4);
    float* red4 = (float*)alloc((size_t)4 * NB * ND * 4);  // mup, s2p, Ahb, zAb contiguous
    float* mup = red4;
    float* s2p = red4 + NB * ND;
    float* Ahb = red4 + 2 * NB * ND;
    float* zAb = red4 + 3 * NB * ND;
    float* sigp = (float*)alloc(NB * ND * 4);
    float* Cb = (float*)alloc(NB * ND * 4);
    float* stopf = (float*)alloc(32);
    float* embt = (float*)alloc(NB * NE * 4);

    // ---- pre-pass ----
    hipMemsetAsync(mu0, 0, (size_t)NB * ND * 4, stream);
    hipMemsetAsync(sig0, 0, (size_t)NB * ND * 4, stream);
    hipMemsetAsync(biasb, 0, (size_t)NB * NP * 4, stream);
    k_colstats<<<dim3(ND / 256, NB, 12), 256, 0, stream>>>(h, mu0, sig0);
    k_stats_fin<<<dim3(NB * ND / 256), 256, 0, stream>>>(mu0, sig0);
    k_energy<<<dim3(NT, NB), 256, 0, stream>>>(h, emask);
    k_w2r<<<dim3(NP + 1), 256, 0, stream>>>(W2, b2, w2r, b2m);
    k_biasb<<<dim3(NP / 256, 8), 256, 0, stream>>>(W1, mu0, sig0, biasb);
    k_split_w<<<dim3(8, 48), 256, 0, stream>>>(W1, NP, 48, w1t_h, w1t_l);
    k_split_w<<<dim3(12, 32), 256, 0, stream>>>(W2, ND, 32, w2t_h, w2t_l);
    k_gemm_mfma<false><<<dim3(12, 8, NB), 256, 0, stream>>>(
        h, nullptr, nullptr, w1t_h, w1t_l, biasb, base, nullptr,
        nullptr, nullptr, nullptr, nullptr);
    k_init<<<dim3(ND / 256, NB), 256, 0, stream>>>(Cb, C0, stopf);

    // ---- iterations ----
    for (int i = 0; i < NITER; ++i) {
        hipMemsetAsync(cvec, 0, (size_t)NB * NP * 4, stream);
        k_cvec<<<dim3(NP / 256, 8), 256, 0, stream>>>(Cb, Wc, cvec);
        k_att<<<dim3(NT, NB), 256, 0, stream>>>(base, cvec, w2r, b2m, emask, att);
        k_softmax<<<dim3(NB), 256, 0, stream>>>(att, Abuf);
        k_split_relu<<<dim3(12, 32, NB), 256, 0, stream>>>(base, cvec, rel_h, rel_l);
        hipMemsetAsync(red4, 0, (size_t)4 * NB * ND * 4, stream);
        k_gemm_mfma<true><<<dim3(12, 12, NB), 256, 0, stream>>>(
            h, rel_h, rel_l, w2t_h, w2t_l, b2, nullptr, Abuf,
            mup, s2p, zAb, Ahb);
        k_sigma<<<dim3(NB * ND / 256), 256, 0, stream>>>(mup, s2p, sigp);
        hipMemsetAsync(embt, 0, (size_t)NB * NE * 4, stream);
        k_embacc<<<dim3(16), 192, 0, stream>>>(mup, sigp, w0, embt);
        k_embnorm<<<dim3(NB), 256, 0, stream>>>(embt, b0, Eout, i);
        k_stop<<<dim3(NB), 256, 0, stream>>>(zAb, Ahb, Cb, stopf, Wstop, bstop, thr, Pout, i);
    }
    k_mask<<<dim3(NB), 192, 0, stream>>>(Eout, Pout, thr);
}